// Round 3
// baseline (697.489 us; speedup 1.0000x reference)
//
#include <hip/hip_runtime.h>
#include <hip/hip_bf16.h>

#define IN_F   4096
#define OUT_F  4096
#define PACKED (IN_F / 8)      // 512
#define M_DIM  8192            // 4 * 2048
#define N_DIM  4096
#define K_DIM  4096

#define BM 256
#define BN 256
#define BK 64
#define NT (K_DIM / BK)        // 64 K-tiles

typedef __bf16 bf16x8 __attribute__((ext_vector_type(8)));
typedef float  f32x4  __attribute__((ext_vector_type(4)));

#define BAR() asm volatile("s_barrier" ::: "memory")
#define VMCNT(n) asm volatile("s_waitcnt vmcnt(" #n ")" ::: "memory")

// ---------------------------------------------------------------------------
// Pre-pass 1: dequantize int4 -> bf16, W[N][K] row-major (B^T layout).
// ---------------------------------------------------------------------------
__global__ __launch_bounds__(256) void dequant_kernel(
    const int* __restrict__ qw, const float* __restrict__ qs,
    const int* __restrict__ qz, __bf16* __restrict__ W)
{
    int t = blockIdx.x * blockDim.x + threadIdx.x;
    if (t >= OUT_F * PACKED) return;
    int o = t >> 9;
    int c = t & (PACKED - 1);
    int g = c >> 4;
    unsigned int q = (unsigned int)qw[t];
    float scale = qs[g * OUT_F + o];
    float zero  = (float)qz[g * OUT_F + o];
    bf16x8 v;
#pragma unroll
    for (int i = 0; i < 8; ++i) {
        float wi = (float)((q >> (4 * i)) & 15u);
        v[i] = (__bf16)((wi - zero) * scale);
    }
    *reinterpret_cast<bf16x8*>(&W[(size_t)t * 8]) = v;
}

// ---------------------------------------------------------------------------
// Pre-pass 2: x f32 -> bf16 (RNE), 8 elements/thread.
// ---------------------------------------------------------------------------
__global__ __launch_bounds__(256) void cvt_kernel(
    const float* __restrict__ x, __bf16* __restrict__ xb, int n8)
{
    int t = blockIdx.x * blockDim.x + threadIdx.x;
    if (t >= n8) return;
    const float4* xv = reinterpret_cast<const float4*>(x);
    float4 a = xv[2 * t];
    float4 b = xv[2 * t + 1];
    bf16x8 v;
    v[0] = (__bf16)a.x; v[1] = (__bf16)a.y; v[2] = (__bf16)a.z; v[3] = (__bf16)a.w;
    v[4] = (__bf16)b.x; v[5] = (__bf16)b.y; v[6] = (__bf16)b.z; v[7] = (__bf16)b.w;
    reinterpret_cast<bf16x8*>(xb)[t] = v;
}

// ---------------------------------------------------------------------------
// Fragment read helpers (LDS is fragment-ordered 16x32 subtiles, 1024 B each;
// a subtile read is a perfectly linear 64-lane x 16 B ds_read_b128).
// ---------------------------------------------------------------------------
__device__ __forceinline__ void read_A4(bf16x8 (&dst)[4][2], const __bf16* base,
                                        int rb0, int lane8)
{
#pragma unroll
    for (int mi = 0; mi < 4; ++mi)
#pragma unroll
        for (int kb = 0; kb < 2; ++kb)
            dst[mi][kb] = *reinterpret_cast<const bf16x8*>(
                base + (((rb0 + mi) * 2 + kb) * 512 + lane8));
}

__device__ __forceinline__ void read_B2(bf16x8 (&dst)[2][2], const __bf16* base,
                                        int rb0, int lane8)
{
#pragma unroll
    for (int ni = 0; ni < 2; ++ni)
#pragma unroll
        for (int kb = 0; kb < 2; ++kb)
            dst[ni][kb] = *reinterpret_cast<const bf16x8*>(
                base + (((rb0 + ni) * 2 + kb) * 512 + lane8));
}

__device__ __forceinline__ void mfma_q(f32x4 (&acc)[8][4], const bf16x8 (&A)[4][2],
                                       const bf16x8 (&B)[2][2], int r0, int c0)
{
#pragma unroll
    for (int kb = 0; kb < 2; ++kb)
#pragma unroll
        for (int mi = 0; mi < 4; ++mi)
#pragma unroll
            for (int ni = 0; ni < 2; ++ni)
                acc[r0 + mi][c0 + ni] = __builtin_amdgcn_mfma_f32_16x16x32_bf16(
                    A[mi][kb], B[ni][kb], acc[r0 + mi][c0 + ni], 0, 0, 0);
}

// ---------------------------------------------------------------------------
// GEMM: 256x256 tile, BK=64, 8 waves (2Mx4N). 4 phases/K-tile, 2 K-tiles per
// loop iter (static buffer/fragment-set selection). One-phase-ahead fragment
// pipelining: ds_reads for phase p+1 issue during phase p. Stage schedule
// p0:B0(t+1) p1:B1(t+1) p2:A0(t+2) p3:A1(t+2); counted vmcnt(4)/(2) placed
// before the post-MFMA barrier (publish-then-read discipline).
// ---------------------------------------------------------------------------
__global__ __launch_bounds__(512, 2) void gemm_kernel(
    const __bf16* __restrict__ A, const __bf16* __restrict__ B,
    float* __restrict__ C)
{
    extern __shared__ __bf16 lds[];   // 2 bufs x (A 16384 + B 16384) = 128 KiB

    const int tid  = threadIdx.x;
    const int lane = tid & 63;
    const int wave = tid >> 6;        // 0..7
    const int wm   = wave >> 2;       // 0..1  (128-row block)
    const int wn   = wave & 3;        // 0..3  (64-col block)
    const int wm8  = wm * 8;
    const int wn4  = wn * 4;
    const int lane8 = lane * 8;

    // bijective XCD swizzle: 512 blocks = 8 XCDs x 64
    const int bid = blockIdx.x;
    const int swz = (bid & 7) * 64 + (bid >> 3);
    const int nBase = (swz & 15) * BN;
    const int mBase = (swz >> 4) * BM;

    const int lr = lane & 15;
    const int lk = (lane >> 4) * 8;

    __bf16* bufA0 = lds;
    __bf16* bufB0 = lds + 16384;
    __bf16* bufA1 = lds + 32768;
    __bf16* bufB1 = lds + 49152;

    auto stage_half = [&](const __bf16* __restrict__ src, __bf16* dstMat,
                          int rowBase, int k0, int hh) {
#pragma unroll
        for (int i = 0; i < 2; ++i) {
            const int st = hh * 16 + i * 8 + wave;        // wave-uniform
            const int r  = (st >> 1) * 16 + lr;
            const int c  = (st & 1) * 32 + lk;
            __builtin_amdgcn_global_load_lds(
                (const __attribute__((address_space(1))) void*)(src + (size_t)(rowBase + r) * K_DIM + (k0 + c)),
                (__attribute__((address_space(3))) void*)(dstMat + st * 512 + lane * 8), 16, 0, 0);
        }
    };

    f32x4 acc[8][4];
#pragma unroll
    for (int i = 0; i < 8; ++i)
#pragma unroll
        for (int j = 0; j < 4; ++j)
            acc[i][j] = 0.0f;

    bf16x8 fA03a[4][2], fA03b[4][2], fA47[4][2];
    bf16x8 fB01a[2][2], fB01b[2][2], fB23[2][2];

    // Prologue: tile0 (4 halves -> buf0) + A(1) (2 halves -> buf1); 12 loads.
    stage_half(A, bufA0, mBase, 0, 0);
    stage_half(A, bufA0, mBase, 0, 1);
    stage_half(B, bufB0, nBase, 0, 0);
    stage_half(B, bufB0, nBase, 0, 1);
    stage_half(A, bufA1, mBase, BK, 0);
    stage_half(A, bufA1, mBase, BK, 1);
    VMCNT(4);                      // tile-0 halves done; A(1) in flight
    BAR();
    read_A4(fA03a, bufA0, wm8 + 0, lane8);
    read_B2(fB01a, bufB0, wn4 + 0, lane8);

    for (int i2 = 0; i2 < NT / 2; ++i2) {
        const int te = 2 * i2;
        const bool sA_e = (te + 2) < NT;   // stage A(te+2) ?
        const bool sO   = (te + 2) < NT;   // odd tile stages B(te+2)
        const bool sA_o = (te + 3) < NT;   // stage A(te+3) ?

        // ======== EVEN tile te (cur=buf0, nxt=buf1; consumes fA03a,fB01a) ====
        // p0: read B23<-buf0 (for Q1/Q2); stage B0(te+1)->buf1; MFMA Q0
        read_B2(fB23, bufB0, wn4 + 2, lane8);
        __builtin_amdgcn_sched_barrier(0);
        stage_half(B, bufB1, nBase, (te + 1) * BK, 0);
        BAR();
        __builtin_amdgcn_s_setprio(1);
        mfma_q(acc, fA03a, fB01a, 0, 0);
        __builtin_amdgcn_s_setprio(0);
        BAR();

        // p1: read A47<-buf0; stage B1(te+1)->buf1; MFMA Q1; vmcnt(4) publishes A(te+1)
        read_A4(fA47, bufA0, wm8 + 4, lane8);
        __builtin_amdgcn_sched_barrier(0);
        stage_half(B, bufB1, nBase, (te + 1) * BK, 1);
        BAR();
        __builtin_amdgcn_s_setprio(1);
        mfma_q(acc, fA03a, fB23, 0, 2);
        __builtin_amdgcn_s_setprio(0);
        VMCNT(4);
        BAR();

        // p2: read A03b<-buf1 (tile te+1); stage A0(te+2)->buf0; MFMA Q2; vmcnt publishes B(te+1)
        read_A4(fA03b, bufA1, wm8 + 0, lane8);
        __builtin_amdgcn_sched_barrier(0);
        if (sA_e) stage_half(A, bufA0, mBase, (te + 2) * BK, 0);
        BAR();
        __builtin_amdgcn_s_setprio(1);
        mfma_q(acc, fA47, fB23, 4, 2);
        __builtin_amdgcn_s_setprio(0);
        if (sA_e) { VMCNT(2); } else { VMCNT(0); }
        BAR();

        // p3: read B01b<-buf1 (tile te+1); stage A1(te+2)->buf0; MFMA Q3
        read_B2(fB01b, bufB1, wn4 + 0, lane8);
        __builtin_amdgcn_sched_barrier(0);
        if (sA_e) stage_half(A, bufA0, mBase, (te + 2) * BK, 1);
        BAR();
        __builtin_amdgcn_s_setprio(1);
        mfma_q(acc, fA47, fB01a, 4, 0);
        __builtin_amdgcn_s_setprio(0);
        BAR();

        // ======== ODD tile te+1 (cur=buf1, nxt=buf0; consumes fA03b,fB01b) ===
        // p0: read B23<-buf1; stage B0(te+2)->buf0; MFMA Q0
        read_B2(fB23, bufB1, wn4 + 2, lane8);
        __builtin_amdgcn_sched_barrier(0);
        if (sO) stage_half(B, bufB0, nBase, (te + 2) * BK, 0);
        BAR();
        __builtin_amdgcn_s_setprio(1);
        mfma_q(acc, fA03b, fB01b, 0, 0);
        __builtin_amdgcn_s_setprio(0);
        BAR();

        // p1: read A47<-buf1; stage B1(te+2)->buf0; MFMA Q1; vmcnt(4) publishes A(te+2)
        read_A4(fA47, bufA1, wm8 + 4, lane8);
        __builtin_amdgcn_sched_barrier(0);
        if (sO) stage_half(B, bufB0, nBase, (te + 2) * BK, 1);
        BAR();
        __builtin_amdgcn_s_setprio(1);
        mfma_q(acc, fA03b, fB23, 0, 2);
        __builtin_amdgcn_s_setprio(0);
        VMCNT(4);
        BAR();

        // p2: read A03a<-buf0 (tile te+2); stage A0(te+3)->buf1; MFMA Q2; vmcnt publishes B(te+2)
        read_A4(fA03a, bufA0, wm8 + 0, lane8);
        __builtin_amdgcn_sched_barrier(0);
        if (sA_o) stage_half(A, bufA1, mBase, (te + 3) * BK, 0);
        BAR();
        __builtin_amdgcn_s_setprio(1);
        mfma_q(acc, fA47, fB23, 4, 2);
        __builtin_amdgcn_s_setprio(0);
        if (sA_o) { VMCNT(2); } else { VMCNT(0); }
        BAR();

        // p3: read B01a<-buf0 (tile te+2); stage A1(te+3)->buf1; MFMA Q3
        read_B2(fB01a, bufB0, wn4 + 0, lane8);
        __builtin_amdgcn_sched_barrier(0);
        if (sA_o) stage_half(A, bufA1, mBase, (te + 3) * BK, 1);
        BAR();
        __builtin_amdgcn_s_setprio(1);
        mfma_q(acc, fA47, fB01b, 4, 0);
        __builtin_amdgcn_s_setprio(0);
        BAR();
    }

    // Epilogue: C/D layout col=lane&15, row=(lane>>4)*4+reg
#pragma unroll
    for (int mi = 0; mi < 8; ++mi)
#pragma unroll
        for (int ni = 0; ni < 4; ++ni) {
            const int col = nBase + wn * 64 + ni * 16 + lr;
#pragma unroll
            for (int r = 0; r < 4; ++r) {
                const int row = mBase + wm * 128 + mi * 16 + (lane >> 4) * 4 + r;
                C[(size_t)row * N_DIM + col] = (float)(__bf16)acc[mi][ni][r];
            }
        }
}

extern "C" void kernel_launch(void* const* d_in, const int* in_sizes, int n_in,
                              void* d_out, int out_size, void* d_ws, size_t ws_size,
                              hipStream_t stream)
{
    const float* x       = (const float*)d_in[0];
    const int*   qweight = (const int*)d_in[1];
    const float* qscale  = (const float*)d_in[2];
    const int*   qzeros  = (const int*)d_in[3];
    float*       out     = (float*)d_out;

    __bf16* W  = (__bf16*)d_ws;
    __bf16* xb = (__bf16*)((char*)d_ws + (size_t)N_DIM * K_DIM * sizeof(__bf16));

    {
        int total = OUT_F * PACKED;
        dequant_kernel<<<(total + 255) / 256, 256, 0, stream>>>(qweight, qscale, qzeros, W);
    }
    {
        int n8 = (M_DIM * K_DIM) / 8;
        cvt_kernel<<<(n8 + 255) / 256, 256, 0, stream>>>(x, xb, n8);
    }
    {
        (void)hipFuncSetAttribute((const void*)gemm_kernel,
                                  hipFuncAttributeMaxDynamicSharedMemorySize, 131072);
        dim3 grid((M_DIM / BM) * (N_DIM / BN));   // 512 blocks
        gemm_kernel<<<grid, 512, 131072, stream>>>(xb, W, out);
    }
}

// Round 4
// 276.730 us; speedup vs baseline: 2.5205x; 2.5205x over previous
//
#include <hip/hip_runtime.h>
#include <hip/hip_bf16.h>

#define IN_F   4096
#define OUT_F  4096
#define PACKED (IN_F / 8)      // 512
#define M_DIM  8192            // 4 * 2048
#define N_DIM  4096
#define K_DIM  4096

#define BM 256
#define BN 256
#define BK 64
#define NT (K_DIM / BK)        // 64 K-tiles
#define NHALF (4 * NT)

typedef __bf16 bf16x8 __attribute__((ext_vector_type(8)));
typedef float  f32x4  __attribute__((ext_vector_type(4)));

#define BAR() asm volatile("s_barrier" ::: "memory")
#define VMCNT(n) asm volatile("s_waitcnt vmcnt(" #n ")" ::: "memory")

// ---------------------------------------------------------------------------
// Fragment-ordered DRAM layout for both GEMM operands (produced by prepasses):
//   [128-row-half][kTile(64)][subtile st(16)][1024 B]
//   subtile st: rows (st>>1)*16..+15 (within the half), cols (st&1)*32..+31
//   within subtile, chunk l (=byte/16): row16 = l&15, k8 = (l>>4)*8
// A wave staging a subtile reads a CONTIGUOUS 1 KB; ds_read_b128 fragment
// reads are lane-linear (0 bank conflicts).
// chunk ch -> (rowHalf, kTile, st, l): l=ch&63, st=(ch>>6)&15,
//   kTile=(ch>>10)&63, rowHalf=ch>>16
// ---------------------------------------------------------------------------

// Pre-pass 1: dequantize int4 -> bf16 fragment-ordered W.
// One chunk (bf16x8) = exactly one qweight int32.
__global__ __launch_bounds__(256) void dequant_kernel(
    const int* __restrict__ qw, const float* __restrict__ qs,
    const int* __restrict__ qz, __bf16* __restrict__ W)
{
    int ch = blockIdx.x * blockDim.x + threadIdx.x;
    if (ch >= OUT_F * PACKED) return;
    int l     = ch & 63;
    int st    = (ch >> 6) & 15;
    int kTile = (ch >> 10) & 63;
    int nHalf = ch >> 16;
    int o  = nHalf * 128 + ((st >> 1) << 4) + (l & 15);
    int k0 = kTile * 64 + ((st & 1) << 5) + ((l >> 4) << 3);
    int g  = k0 >> 7;
    unsigned int q = (unsigned int)qw[o * PACKED + (k0 >> 3)];
    float scale = qs[g * OUT_F + o];
    float zero  = (float)qz[g * OUT_F + o];
    bf16x8 v;
#pragma unroll
    for (int i = 0; i < 8; ++i) {
        float wi = (float)((q >> (4 * i)) & 15u);
        v[i] = (__bf16)((wi - zero) * scale);
    }
    *reinterpret_cast<bf16x8*>(&W[(size_t)ch * 8]) = v;
}

// Pre-pass 2: x f32 -> bf16 fragment-ordered xb.
__global__ __launch_bounds__(256) void cvt_kernel(
    const float* __restrict__ x, __bf16* __restrict__ xb, int nch)
{
    int ch = blockIdx.x * blockDim.x + threadIdx.x;
    if (ch >= nch) return;
    int l     = ch & 63;
    int st    = (ch >> 6) & 15;
    int kTile = (ch >> 10) & 63;
    int mHalf = ch >> 16;
    int m  = mHalf * 128 + ((st >> 1) << 4) + (l & 15);
    int k0 = kTile * 64 + ((st & 1) << 5) + ((l >> 4) << 3);
    const float4* xv = reinterpret_cast<const float4*>(x + (size_t)m * K_DIM + k0);
    float4 a = xv[0];
    float4 b = xv[1];
    bf16x8 v;
    v[0] = (__bf16)a.x; v[1] = (__bf16)a.y; v[2] = (__bf16)a.z; v[3] = (__bf16)a.w;
    v[4] = (__bf16)b.x; v[5] = (__bf16)b.y; v[6] = (__bf16)b.z; v[7] = (__bf16)b.w;
    reinterpret_cast<bf16x8*>(xb)[ch] = v;
}

// ---------------------------------------------------------------------------
// GEMM: 256x256 tile, BK=64, 8 waves (2Mx4N), 4 phases/K-tile, counted
// vmcnt(6), setprio around MFMA. Round-2 schedule (verified race-free);
// staging source is now contiguous per subtile.
// ---------------------------------------------------------------------------
__global__ __launch_bounds__(512, 2) void gemm_kernel(
    const __bf16* __restrict__ A, const __bf16* __restrict__ B,
    float* __restrict__ C)
{
    extern __shared__ __bf16 lds[];   // 2 bufs x (A 16384 + B 16384) = 128 KiB

    const int tid  = threadIdx.x;
    const int lane = tid & 63;
    const int wave = tid >> 6;        // 0..7
    const int wm   = wave >> 2;       // 0..1
    const int wn   = wave & 3;        // 0..3

    // bijective XCD swizzle: 512 blocks = 8 XCDs x 64
    const int bid = blockIdx.x;
    const int swz = (bid & 7) * 64 + (bid >> 3);
    const int nBase = (swz & 15) * BN;
    const int mBase = (swz >> 4) * BM;
    const int mHalf0 = mBase >> 7;    // global 128-half index of tile row 0
    const int nHalf0 = nBase >> 7;

    const int lr = lane & 15;

    // stage one 128x64 half-tile (16 subtiles): 2 contiguous-1KB loads/thread
    auto stage_half = [&](const __bf16* __restrict__ srcFrag, __bf16* dstMat,
                          int halfGlobal, int kTile, int hh) {
        const __bf16* base = srcFrag + ((size_t)(halfGlobal * 64 + kTile) << 13);
#pragma unroll
        for (int i = 0; i < 2; ++i) {
            const int st = i * 8 + wave;          // wave-uniform
            __builtin_amdgcn_global_load_lds(
                (const __attribute__((address_space(1))) void*)(base + st * 512 + lane * 8),
                (__attribute__((address_space(3))) void*)(dstMat + (hh * 16 + st) * 512 + lane * 8),
                16, 0, 0);
        }
    };
    // half order per tile: 0=A rows0-127, 1=A rows128-255, 2=B 0-127, 3=B 128-255
    auto stage_H = [&](int H) {
        const int t = H >> 2;
        const int h = H & 3;
        __bf16* base = lds + (size_t)(t & 1) * 32768 + (size_t)(h >> 1) * 16384;
        if (h & 2) stage_half(B, base, nHalf0 + (h & 1), t, h & 1);
        else       stage_half(A, base, mHalf0 + (h & 1), t, h & 1);
    };

    f32x4 acc[8][4];
#pragma unroll
    for (int i = 0; i < 8; ++i)
#pragma unroll
        for (int j = 0; j < 4; ++j)
            acc[i][j] = 0.0f;

    // prologue: tile0 all 4 halves + tile1 halves A0,A1,B0
#pragma unroll
    for (int H = 0; H < 7; ++H) stage_H(H);
    VMCNT(6);                          // tile0 complete, 3 half-tiles in flight
    BAR();

#define LDA(mi, kb) (*(const bf16x8*)(lA + (((wm * 8 + (mi)) * 2 + (kb)) * 512 + lane * 8)))
#define LDB(ni, kb) (*(const bf16x8*)(lB + (((wn * 4 + (ni)) * 2 + (kb)) * 512 + lane * 8)))

    for (int t = 0; t < NT; ++t) {
        const __bf16* lA = lds + (size_t)(t & 1) * 32768;
        const __bf16* lB = lA + 16384;
        const int Hb = 4 * t + 7;     // stage lead = +7 halves
        bf16x8 Af[8][2];
        bf16x8 Bf[2][2];

        // p0: read A mi0-3 + B ni0-1 (12 ds_read); stage (t+1,B1); MFMA Q0
#pragma unroll
        for (int mi = 0; mi < 4; ++mi) { Af[mi][0] = LDA(mi, 0); Af[mi][1] = LDA(mi, 1); }
#pragma unroll
        for (int ni = 0; ni < 2; ++ni) { Bf[ni][0] = LDB(ni, 0); Bf[ni][1] = LDB(ni, 1); }
        __builtin_amdgcn_sched_barrier(0);
        if (Hb < NHALF) stage_H(Hb);
        BAR();
        __builtin_amdgcn_s_setprio(1);
#pragma unroll
        for (int kb = 0; kb < 2; ++kb)
#pragma unroll
            for (int mi = 0; mi < 4; ++mi)
#pragma unroll
                for (int ni = 0; ni < 2; ++ni)
                    acc[mi][ni] = __builtin_amdgcn_mfma_f32_16x16x32_bf16(Af[mi][kb], Bf[ni][kb], acc[mi][ni], 0, 0, 0);
        __builtin_amdgcn_s_setprio(0);
        BAR();

        // p1: read A mi4-7 (8 ds_read); stage (t+2,A0); MFMA Q1
#pragma unroll
        for (int mi = 4; mi < 8; ++mi) { Af[mi][0] = LDA(mi, 0); Af[mi][1] = LDA(mi, 1); }
        __builtin_amdgcn_sched_barrier(0);
        if (Hb + 1 < NHALF) stage_H(Hb + 1);
        BAR();
        __builtin_amdgcn_s_setprio(1);
#pragma unroll
        for (int kb = 0; kb < 2; ++kb)
#pragma unroll
            for (int mi = 4; mi < 8; ++mi)
#pragma unroll
                for (int ni = 0; ni < 2; ++ni)
                    acc[mi][ni] = __builtin_amdgcn_mfma_f32_16x16x32_bf16(Af[mi][kb], Bf[ni][kb], acc[mi][ni], 0, 0, 0);
        __builtin_amdgcn_s_setprio(0);
        BAR();

        // p2: read B ni2-3 (4 ds_read, overwrite Bf); stage (t+2,A1); MFMA Q2
#pragma unroll
        for (int ni = 0; ni < 2; ++ni) { Bf[ni][0] = LDB(ni + 2, 0); Bf[ni][1] = LDB(ni + 2, 1); }
        __builtin_amdgcn_sched_barrier(0);
        if (Hb + 2 < NHALF) stage_H(Hb + 2);
        BAR();
        __builtin_amdgcn_s_setprio(1);
#pragma unroll
        for (int kb = 0; kb < 2; ++kb)
#pragma unroll
            for (int mi = 0; mi < 4; ++mi)
#pragma unroll
                for (int nj = 0; nj < 2; ++nj)
                    acc[mi][nj + 2] = __builtin_amdgcn_mfma_f32_16x16x32_bf16(Af[mi][kb], Bf[nj][kb], acc[mi][nj + 2], 0, 0, 0);
        __builtin_amdgcn_s_setprio(0);
        BAR();

        // p3: no ds_read; stage (t+2,B0); MFMA Q3; counted vmcnt; bar
        if (Hb + 3 < NHALF) stage_H(Hb + 3);
        BAR();
        __builtin_amdgcn_s_setprio(1);
#pragma unroll
        for (int kb = 0; kb < 2; ++kb)
#pragma unroll
            for (int mi = 4; mi < 8; ++mi)
#pragma unroll
                for (int nj = 0; nj < 2; ++nj)
                    acc[mi][nj + 2] = __builtin_amdgcn_mfma_f32_16x16x32_bf16(Af[mi][kb], Bf[nj][kb], acc[mi][nj + 2], 0, 0, 0);
        __builtin_amdgcn_s_setprio(0);
        if (t < NT - 2)       VMCNT(6);   // tile t+1 fully landed, 3 halves in flight
        else if (t == NT - 2) VMCNT(0);   // final drain
        BAR();
    }

    // Epilogue: C/D layout col=lane&15, row=(lane>>4)*4+reg
#pragma unroll
    for (int mi = 0; mi < 8; ++mi)
#pragma unroll
        for (int ni = 0; ni < 4; ++ni) {
            const int col = nBase + wn * 64 + ni * 16 + lr;
#pragma unroll
            for (int r = 0; r < 4; ++r) {
                const int row = mBase + wm * 128 + mi * 16 + (lane >> 4) * 4 + r;
                C[(size_t)row * N_DIM + col] = (float)(__bf16)acc[mi][ni][r];
            }
        }
#undef LDA
#undef LDB
}

extern "C" void kernel_launch(void* const* d_in, const int* in_sizes, int n_in,
                              void* d_out, int out_size, void* d_ws, size_t ws_size,
                              hipStream_t stream)
{
    const float* x       = (const float*)d_in[0];
    const int*   qweight = (const int*)d_in[1];
    const float* qscale  = (const float*)d_in[2];
    const int*   qzeros  = (const int*)d_in[3];
    float*       out     = (float*)d_out;

    __bf16* W  = (__bf16*)d_ws;
    __bf16* xb = (__bf16*)((char*)d_ws + (size_t)N_DIM * K_DIM * sizeof(__bf16));

    {
        int total = OUT_F * PACKED;            // 2,097,152 chunks
        dequant_kernel<<<(total + 255) / 256, 256, 0, stream>>>(qweight, qscale, qzeros, W);
    }
    {
        int nch = (M_DIM * K_DIM) / 8;         // 4,194,304 chunks
        cvt_kernel<<<(nch + 255) / 256, 256, 0, stream>>>(x, xb, nch);
    }
    {
        (void)hipFuncSetAttribute((const void*)gemm_kernel,
                                  hipFuncAttributeMaxDynamicSharedMemorySize, 131072);
        dim3 grid((M_DIM / BM) * (N_DIM / BN));   // 512 blocks
        gemm_kernel<<<grid, 512, 131072, stream>>>(xb, W, out);
    }
}